// Round 1
// 526.279 us; speedup vs baseline: 1.0406x; 1.0406x over previous
//
#include <hip/hip_runtime.h>
#include <math.h>

#define B_      2
#define N_      4096
#define H_      1024
#define HEADS_  16
#define DH_     64
#define M_      256
#define NSPLIT  8
#define EPAD    80

constexpr float NORMALIZER = 0.35355339059327373f; // 64^-0.25
constexpr float RATIO      = 0.0625f;              // 256^-0.5
constexpr float KEPS       = 1e-3f;

typedef __bf16 bf16x8 __attribute__((ext_vector_type(8)));
typedef __bf16 bf16x4 __attribute__((ext_vector_type(4)));
typedef float  f32x4  __attribute__((ext_vector_type(4)));

// ======================================================================
// Split fp32 -> bf16 (hi, lo)
// ======================================================================
__global__ __launch_bounds__(256) void split_bf16(
    const float* __restrict__ src, __bf16* __restrict__ hi, __bf16* __restrict__ lo)
{
    int i = blockIdx.x * 256 + threadIdx.x;
    float4 v = ((const float4*)src)[i];
    float vv[4] = {v.x, v.y, v.z, v.w};
    bf16x4 h, l;
#pragma unroll
    for (int j = 0; j < 4; ++j) {
        __bf16 hh = (__bf16)vv[j];
        h[j] = hh;
        l[j] = (__bf16)(vv[j] - (float)hh);
    }
    ((bf16x4*)hi)[i] = h;
    ((bf16x4*)lo)[i] = l;
}

__global__ __launch_bounds__(256) void split_w(
    const float* __restrict__ W0, const float* __restrict__ W1,
    const float* __restrict__ W2, const float* __restrict__ W3,
    __bf16* __restrict__ hi, __bf16* __restrict__ lo)
{
    const float* src = W0;
    if (blockIdx.y == 1) src = W1;
    else if (blockIdx.y == 2) src = W2;
    else if (blockIdx.y == 3) src = W3;
    int i = blockIdx.x * 256 + threadIdx.x;
    size_t o = (size_t)blockIdx.y * 262144 + i;
    float4 v = ((const float4*)src)[i];
    float vv[4] = {v.x, v.y, v.z, v.w};
    bf16x4 h, l;
#pragma unroll
    for (int j = 0; j < 4; ++j) {
        __bf16 hh = (__bf16)vv[j];
        h[j] = hh;
        l[j] = (__bf16)(vv[j] - (float)hh);
    }
    ((bf16x4*)hi)[o] = h;
    ((bf16x4*)lo)[o] = l;
}

// ======================================================================
// Split-bf16 MFMA GEMM, C = A@W^T + bias. BF16OUT: write C as bf16 hi/lo.
// 2-phase pipelined K-loop:
//   - global_load_lds width=16 direct staging (no VGPR roundtrip)
//   - double-buffered linear LDS tiles [128][32] (64 KiB total, 2 blk/CU)
//   - counted s_waitcnt vmcnt(8): next tile's 8 loads stay in flight
//     across both barriers (raw s_barrier; no vmcnt(0) drain in loop)
//   - XOR swizzle (chunk ^= (row>>1)&3) applied to the GLOBAL source at
//     staging and to the ds_read address (linear LDS dest, rule #21) ->
//     fragment reads are 2-way (free) instead of 8-way conflicted
// ======================================================================
template<bool BF16OUT>
__global__ __launch_bounds__(256, 2) void gemm_mfma3(
    const __bf16* __restrict__ Ah, const __bf16* __restrict__ Al,
    const __bf16* __restrict__ Bh0, const __bf16* __restrict__ Bl0,
    const __bf16* __restrict__ Bh1, const __bf16* __restrict__ Bl1,
    const __bf16* __restrict__ Bh2, const __bf16* __restrict__ Bl2,
    const float* __restrict__ bi0, const float* __restrict__ bi1, const float* __restrict__ bi2,
    float* __restrict__ C0,
    __bf16* __restrict__ Ch0, __bf16* __restrict__ Cl0,
    __bf16* __restrict__ Ch1, __bf16* __restrict__ Cl1,
    __bf16* __restrict__ Ch2, __bf16* __restrict__ Cl2)
{
    const __bf16* Bh = Bh0; const __bf16* Bl = Bl0; const float* bias = bi0;
    __bf16* Ch = Ch0; __bf16* Cl = Cl0;
    if (blockIdx.z == 1) { Bh = Bh1; Bl = Bl1; bias = bi1; Ch = Ch1; Cl = Cl1; }
    else if (blockIdx.z == 2) { Bh = Bh2; Bl = Bl2; bias = bi2; Ch = Ch2; Cl = Cl2; }

    // [buf][tile][128*32] linear; tile: 0=Ah 1=Al 2=Bh 3=Bl
    __shared__ alignas(16) __bf16 lds[2][4][128 * 32];

    const int t    = threadIdx.x;
    const int lane = t & 63;
    const int lm   = lane & 15;
    const int lq   = lane >> 4;
    const int wave = t >> 6;
    const int wm   = (wave >> 1) * 64;
    const int wn   = (wave & 1) * 64;
    const int m0   = blockIdx.y * 128;
    const int n0   = blockIdx.x * 128;
    const int K    = 1024;
    const int NK   = 32;

    // wave w stages tile w; 8 calls x 1KiB (64 lanes x 16B) per K-step.
    // lane -> (row = c*16 + (lane>>2), slot = lane&3); LDS dest is linear.
    // Global column chunk is pre-swizzled: chunk = slot ^ ((row>>1)&3);
    // since row = c*16 + (lane>>2), (row>>1)&3 == (lane>>3)&3 (c*8 mod 4 == 0).
    const __bf16* mysrc = (wave == 0) ? Ah : (wave == 1) ? Al : (wave == 2) ? Bh : Bl;
    const int     rbase = (wave < 2) ? m0 : n0;
    const int rsub   = lane >> 2;
    const int slot   = lane & 3;
    const int schunk = slot ^ ((lane >> 3) & 3);
    const __bf16* gbase = mysrc + (size_t)(rbase + rsub) * K + schunk * 8;

    f32x4 acc[4][4];
#pragma unroll
    for (int i = 0; i < 4; ++i)
#pragma unroll
        for (int j = 0; j < 4; ++j) acc[i][j] = (f32x4){0.f, 0.f, 0.f, 0.f};

    // read-side swizzle (same involution). Fragment row r = 16*q + lm, so
    // ((r>>1)&3) == ((lm>>1)&3): swz is lane-constant for the whole kernel.
    const int swz = (lq ^ ((lm >> 1) & 3)) * 8;

    auto stage = [&](int buf, int k0) {
#pragma unroll
        for (int c = 0; c < 8; ++c) {
            const __bf16* g = gbase + (size_t)c * 16 * K + k0;
            __builtin_amdgcn_global_load_lds(
                (const __attribute__((address_space(1))) void*)g,
                (__attribute__((address_space(3))) void*)&lds[buf][wave][c * 512],
                16, 0, 0);
        }
    };

    auto compute = [&](int p) {
        const __bf16* tAh = lds[p][0];
        const __bf16* tAl = lds[p][1];
        const __bf16* tBh = lds[p][2];
        const __bf16* tBl = lds[p][3];
        bf16x8 bh[4], bl[4];
#pragma unroll
        for (int j = 0; j < 4; ++j) {
            int off = (wn + j * 16 + lm) * 32 + swz;
            bh[j] = *(const bf16x8*)&tBh[off];
            bl[j] = *(const bf16x8*)&tBl[off];
        }
#pragma unroll
        for (int i = 0; i < 4; ++i) {
            int off = (wm + i * 16 + lm) * 32 + swz;
            bf16x8 ah = *(const bf16x8*)&tAh[off];
            bf16x8 al = *(const bf16x8*)&tAl[off];
#pragma unroll
            for (int j = 0; j < 4; ++j) {
                acc[i][j] = __builtin_amdgcn_mfma_f32_16x16x32_bf16(ah, bh[j], acc[i][j], 0, 0, 0);
                acc[i][j] = __builtin_amdgcn_mfma_f32_16x16x32_bf16(al, bh[j], acc[i][j], 0, 0, 0);
                acc[i][j] = __builtin_amdgcn_mfma_f32_16x16x32_bf16(ah, bl[j], acc[i][j], 0, 0, 0);
            }
        }
    };

    stage(0, 0);
    int p = 0;
#pragma unroll 1
    for (int kk = 0; kk < NK - 1; ++kk) {
        // issue next K-step's loads (safe: prior reads of buf p^1 finished
        // before the trailing barrier of the previous iteration)
        stage(p ^ 1, (kk + 1) * 32);
        // wait only for MY oldest 8 (current buffer); next 8 stay in flight
        asm volatile("s_waitcnt vmcnt(8)" ::: "memory");
        asm volatile("s_barrier" ::: "memory");   // all waves' current tile landed
        compute(p);
        asm volatile("s_barrier" ::: "memory");   // reads done before overwrite
        p ^= 1;
    }
    asm volatile("s_waitcnt vmcnt(0)" ::: "memory");
    asm volatile("s_barrier" ::: "memory");
    compute(p);

    float bsr[4];
#pragma unroll
    for (int j = 0; j < 4; ++j) bsr[j] = bias[n0 + wn + j * 16 + lm];
#pragma unroll
    for (int i = 0; i < 4; ++i)
#pragma unroll
        for (int r = 0; r < 4; ++r) {
            int rowm = m0 + wm + i * 16 + lq * 4 + r;
#pragma unroll
            for (int j = 0; j < 4; ++j) {
                int col = n0 + wn + j * 16 + lm;
                float o = acc[i][j][r] + bsr[j];
                if (BF16OUT) {
                    __bf16 hh = (__bf16)o;
                    Ch[(size_t)rowm * 1024 + col] = hh;
                    Cl[(size_t)rowm * 1024 + col] = (__bf16)(o - (float)hh);
                } else {
                    C0[(size_t)rowm * 1024 + col] = o;
                }
            }
        }
}

// ======================================================================
// diag_k from bf16 hi/lo K
// ======================================================================
__global__ __launch_bounds__(256) void diag_kernel(
    const __bf16* __restrict__ Kh, const __bf16* __restrict__ Kl,
    float* __restrict__ diag, float* __restrict__ partials)
{
    int gt = blockIdx.x * 256 + threadIdx.x;
    int r  = gt >> 2;
    int q  = gt & 3;
    const bf16x8* ph = (const bf16x8*)(Kh + (size_t)r * 64 + q * 16);
    const bf16x8* pl = (const bf16x8*)(Kl + (size_t)r * 64 + q * 16);
    float s = 0.f;
#pragma unroll
    for (int i = 0; i < 2; ++i) {
        bf16x8 vh = ph[i], vl = pl[i];
#pragma unroll
        for (int j = 0; j < 8; ++j) {
            float x = (float)vh[j] + (float)vl[j];
            s += x * x;
        }
    }
    s += __shfl_xor(s, 1);
    s += __shfl_xor(s, 2);
    float d = -0.5f * s;
    if (q == 0) {
        int h = r & 15, bn = r >> 4;
        int n = bn & 4095, b = bn >> 12;
        diag[(((size_t)b * 16 + h) << 12) + n] = d;
    }
    __shared__ float red[256];
    red[threadIdx.x] = d;
    __syncthreads();
    for (int s2 = 128; s2 > 0; s2 >>= 1) {
        if (threadIdx.x < s2) red[threadIdx.x] = fmaxf(red[threadIdx.x], red[threadIdx.x + s2]);
        __syncthreads();
    }
    if (threadIdx.x == 0) partials[blockIdx.x] = red[0];
}

__global__ __launch_bounds__(256) void reduce_stab(
    const float* __restrict__ partials, float* __restrict__ stab, int n)
{
    float m = -3.0e38f;
    for (int i = threadIdx.x; i < n; i += 256) m = fmaxf(m, partials[i]);
    __shared__ float red[256];
    red[threadIdx.x] = m;
    __syncthreads();
    for (int s2 = 128; s2 > 0; s2 >>= 1) {
        if (threadIdx.x < s2) red[threadIdx.x] = fmaxf(red[threadIdx.x], red[threadIdx.x + s2]);
        __syncthreads();
    }
    if (threadIdx.x == 0) stab[0] = red[0];
}

// ======================================================================
// ctx via MFMA. grid (NSPLIT, 2 m-halves, 32 bh). 4 waves, wave owns 32 m.
// dash: D[n64, m32/wave] = K@proj^T (3 split products, operands from global)
// exp -> kf bf16 hi/lo -> LDS transpose kfT[m][n] -> ctx += kfT @ vT[e][n]
// e=64 is ones (k_cumsum); e 65..79 zero pad. fp32 partials out [s][bh][e][m].
// ======================================================================
__global__ __launch_bounds__(256) void ctx_mfma(
    const __bf16* __restrict__ Kh, const __bf16* __restrict__ Kl,
    const __bf16* __restrict__ Vh, const __bf16* __restrict__ Vl,
    const __bf16* __restrict__ projH, const __bf16* __restrict__ projL,
    const float* __restrict__ diag, const float* __restrict__ stabp,
    float* __restrict__ ctxp)
{
    __shared__ alignas(16) char ldsbuf[59904];
    __shared__ float dg[64];
    __bf16* kfTh = (__bf16*)ldsbuf;              // [128][72]
    __bf16* kfTl = kfTh + 9216;                  // [128][72]
    __bf16* vTh  = kfTl + 9216;                  // [80][72]
    __bf16* vTl  = vTh + 5760;                   // [80][72]
    float*  ctxe = (float*)ldsbuf;               // [128][81] (epilogue alias)

    const int t    = threadIdx.x;
    const int lane = t & 63;
    const int w    = t >> 6;
    const int lm   = lane & 15;
    const int lq   = lane >> 4;
    const int bh   = blockIdx.z;
    const int b    = bh >> 4, h = bh & 15;
    const int mh   = blockIdx.y;
    const int slice = blockIdx.x;
    const int mwave = mh * 128 + w * 32;          // global m base for wave
    const float stab = stabp[0];
    const size_t rowbase = (size_t)b * N_ * H_ + (size_t)h * DH_;
    const float* diag_bh = diag + (size_t)bh * N_;

    // vT constant rows: e=64 -> ones (hi), e>64 -> zero
    for (int idx = t; idx < 16 * 72; idx += 256) {
        int e = 64 + idx / 72, n = idx % 72;
        vTh[e * 72 + n] = (e == 64 && n < 64) ? (__bf16)1.0f : (__bf16)0.0f;
        vTl[e * 72 + n] = (__bf16)0.0f;
    }

    // proj B-frags, register-cached for whole kernel: [mf][ks]
    bf16x8 ph[2][2], pl[2][2];
#pragma unroll
    for (int mf = 0; mf < 2; ++mf)
#pragma unroll
        for (int ks = 0; ks < 2; ++ks) {
            size_t pa = (size_t)(mwave + mf * 16 + lm) * 64 + ks * 32 + lq * 8;
            ph[mf][ks] = *(const bf16x8*)(projH + pa);
            pl[mf][ks] = *(const bf16x8*)(projL + pa);
        }

    f32x4 acc[2][5];
#pragma unroll
    for (int mf = 0; mf < 2; ++mf)
#pragma unroll
        for (int ef = 0; ef < 5; ++ef) acc[mf][ef] = (f32x4){0.f, 0.f, 0.f, 0.f};

    for (int tile = 0; tile < 8; ++tile) {
        const int n0 = slice * (N_ / NSPLIT) + tile * 64;
        __syncthreads();   // barrier A: prior GEMM reads of vT done

        // stage vT rows 0..63 (transpose V[n][d] -> vT[d][n])
        {
            int nl = t >> 2, dc = (t & 3) * 16;
            size_t va = rowbase + (size_t)(n0 + nl) * H_ + dc;
            bf16x8 v0 = *(const bf16x8*)(Vh + va);
            bf16x8 v1 = *(const bf16x8*)(Vh + va + 8);
            bf16x8 u0 = *(const bf16x8*)(Vl + va);
            bf16x8 u1 = *(const bf16x8*)(Vl + va + 8);
#pragma unroll
            for (int j = 0; j < 8; ++j) {
                vTh[(dc + j) * 72 + nl]     = v0[j];
                vTh[(dc + 8 + j) * 72 + nl] = v1[j];
                vTl[(dc + j) * 72 + nl]     = u0[j];
                vTl[(dc + 8 + j) * 72 + nl] = u1[j];
            }
        }
        if (t < 64) dg[t] = diag_bh[n0 + t] - stab;

        // dash MFMA (global operands, no LDS dependency)
        f32x4 dsh[4][2];
#pragma unroll
        for (int nf = 0; nf < 4; ++nf) {
#pragma unroll
            for (int mf = 0; mf < 2; ++mf) dsh[nf][mf] = (f32x4){0.f, 0.f, 0.f, 0.f};
            bf16x8 ah[2], al[2];
#pragma unroll
            for (int ks = 0; ks < 2; ++ks) {
                size_t ka = rowbase + (size_t)(n0 + nf * 16 + lm) * H_ + ks * 32 + lq * 8;
                ah[ks] = *(const bf16x8*)(Kh + ka);
                al[ks] = *(const bf16x8*)(Kl + ka);
            }
#pragma unroll
            for (int mf = 0; mf < 2; ++mf)
#pragma unroll
                for (int ks = 0; ks < 2; ++ks) {
                    dsh[nf][mf] = __builtin_amdgcn_mfma_f32_16x16x32_bf16(ah[ks], ph[mf][ks], dsh[nf][mf], 0, 0, 0);
                    dsh[nf][mf] = __builtin_amdgcn_mfma_f32_16x16x32_bf16(al[ks], ph[mf][ks], dsh[nf][mf], 0, 0, 0);
                    dsh[nf][mf] = __builtin_amdgcn_mfma_f32_16x16x32_bf16(ah[ks], pl[mf][ks], dsh[nf][mf], 0, 0, 0);
                }
        }

        __syncthreads();   // barrier B: vT + dg staged

        // exp -> kf bf16 hi/lo -> kfT (wave-private rows)
#pragma unroll
        for (int nf = 0; nf < 4; ++nf) {
            float4 dgv = *(const float4*)&dg[nf * 16 + lq * 4];
            float dga[4] = {dgv.x, dgv.y, dgv.z, dgv.w};
#pragma unroll
            for (int mf = 0; mf < 2; ++mf) {
                int mrow = w * 32 + mf * 16 + lm;   // block-local m row
#pragma unroll
                for (int r = 0; r < 4; ++r) {
                    float kf = RATIO * (__expf(dga[r] + NORMALIZER * dsh[nf][mf][r]) + KEPS);
                    __bf16 hh = (__bf16)kf;
                    int nloc = nf * 16 + lq * 4 + r;
                    kfTh[mrow * 72 + nloc] = hh;
                    kfTl[mrow * 72 + nloc] = (__bf16)(kf - (float)hh);
                }
            }
        }

        // ctx accumulate: acc[mf][ef] += kfT[m][n] @ vT[e][n]
#pragma unroll
        for (int ks = 0; ks < 2; ++ks) {
#pragma unroll
            for (int mf = 0; mf < 2; ++mf) {
                bf16x8 af = *(const bf16x8*)&kfTh[(w * 32 + mf * 16 + lm) * 72 + ks * 32 + lq * 8];
                bf16x8 afl = *(const bf16x8*)&kfTl[(w * 32 + mf * 16 + lm) * 72 + ks * 32 + lq * 8];
#pragma unroll
                for (int ef = 0; ef < 5; ++ef) {
                    bf16x8 bfh = *(const bf16x8*)&vTh[(ef * 16 + lm) * 72 + ks * 32 + lq * 8];
                    bf16x8 bfl = *(const bf16x8*)&vTl[(ef * 16 + lm) * 72 + ks * 32 + lq * 8];
                    acc[mf][ef] = __builtin_amdgcn_mfma_f32_16x16x32_bf16(af,  bfh, acc[mf][ef], 0, 0, 0);
                    acc[mf][ef] = __builtin_amdgcn_mfma_f32_16x16x32_bf16(afl, bfh, acc[mf][ef], 0, 0, 0);
                    acc[mf][ef] = __builtin_amdgcn_mfma_f32_16x16x32_bf16(af,  bfl, acc[mf][ef], 0, 0, 0);
                }
            }
        }
    }

    // epilogue: acc -> ctxe[m][e] (fp32, pad 81) -> coalesced global [s][bh][e][m]
    __syncthreads();
#pragma unroll
    for (int mf = 0; mf < 2; ++mf)
#pragma unroll
        for (int ef = 0; ef < 5; ++ef)
#pragma unroll
            for (int r = 0; r < 4; ++r) {
                int ml = w * 32 + mf * 16 + lq * 4 + r;
                int e  = ef * 16 + lm;
                ctxe[ml * 81 + e] = acc[mf][ef][r];
            }
    __syncthreads();
    const size_t SLICE = (size_t)(B_ * HEADS_) * EPAD * M_;
    const size_t obase = (size_t)slice * SLICE + (size_t)bh * EPAD * M_;
    for (int i = t; i < EPAD * 128; i += 256) {
        int e = i >> 7, ml = i & 127;
        ctxp[obase + (size_t)e * M_ + mh * 128 + ml] = ctxe[ml * 81 + e];
    }
}

// ======================================================================
// Reduce ctx partials over slices -> bf16 hi/lo ctxT[bh][e][m]
// ======================================================================
__global__ __launch_bounds__(256) void ctx_reduce(
    const float* __restrict__ ctxp, __bf16* __restrict__ ctxTh, __bf16* __restrict__ ctxTl)
{
    int idx = blockIdx.x * 256 + threadIdx.x;     // [0, 32*80*256)
    const size_t SLICE = (size_t)(B_ * HEADS_) * EPAD * M_;
    float s = 0.f;
#pragma unroll
    for (int k = 0; k < NSPLIT; ++k) s += ctxp[(size_t)k * SLICE + idx];
    __bf16 hh = (__bf16)s;
    ctxTh[idx] = hh;
    ctxTl[idx] = (__bf16)(s - (float)hh);
}

// ======================================================================
// out via MFMA. grid (N/64, 32 bh). 4 waves, wave owns 16 n rows. No barriers.
// dash D[n16, m64-chunk] -> qf -> wave-private LDS transpose -> acc += qf@ctxT.
// Column 64 of ctxT = k_cumsum -> denominator; shfl-broadcast; bf16 hi/lo out.
// ======================================================================
__global__ __launch_bounds__(256) void out_mfma(
    const __bf16* __restrict__ Qh, const __bf16* __restrict__ Ql,
    const __bf16* __restrict__ projH, const __bf16* __restrict__ projL,
    const __bf16* __restrict__ ctxTh, const __bf16* __restrict__ ctxTl,
    __bf16* __restrict__ attnH, __bf16* __restrict__ attnL)
{
    __shared__ alignas(16) __bf16 qfh[4][16][72];
    __shared__ alignas(16) __bf16 qfl[4][16][72];

    const int t    = threadIdx.x;
    const int lane = t & 63;
    const int w    = t >> 6;
    const int lm   = lane & 15;
    const int lq   = lane >> 4;
    const int bh   = blockIdx.y;
    const int b    = bh >> 4, h = bh & 15;
    const int nw   = blockIdx.x * 64 + w * 16;    // wave's n base
    const size_t rowbase = (size_t)b * N_ * H_ + (size_t)h * DH_;

    // A dash frags (q rows), loaded once
    bf16x8 qh_[2], ql_[2];
#pragma unroll
    for (int ks = 0; ks < 2; ++ks) {
        size_t qa = rowbase + (size_t)(nw + lm) * H_ + ks * 32 + lq * 8;
        qh_[ks] = *(const bf16x8*)(Qh + qa);
        ql_[ks] = *(const bf16x8*)(Ql + qa);
    }

    const __bf16* cth = ctxTh + (size_t)bh * EPAD * M_;
    const __bf16* ctl = ctxTl + (size_t)bh * EPAD * M_;

    f32x4 accO[5];
#pragma unroll
    for (int ef = 0; ef < 5; ++ef) accO[ef] = (f32x4){0.f, 0.f, 0.f, 0.f};

    for (int mc = 0; mc < 4; ++mc) {
        const int m0 = mc * 64;
        // dash
        f32x4 dsh[4];
#pragma unroll
        for (int mf = 0; mf < 4; ++mf) {
            dsh[mf] = (f32x4){0.f, 0.f, 0.f, 0.f};
#pragma unroll
            for (int ks = 0; ks < 2; ++ks) {
                size_t pa = (size_t)(m0 + mf * 16 + lm) * 64 + ks * 32 + lq * 8;
                bf16x8 ph = *(const bf16x8*)(projH + pa);
                bf16x8 pl = *(const bf16x8*)(projL + pa);
                dsh[mf] = __builtin_amdgcn_mfma_f32_16x16x32_bf16(qh_[ks], ph, dsh[mf], 0, 0, 0);
                dsh[mf] = __builtin_amdgcn_mfma_f32_16x16x32_bf16(ql_[ks], ph, dsh[mf], 0, 0, 0);
                dsh[mf] = __builtin_amdgcn_mfma_f32_16x16x32_bf16(qh_[ks], pl, dsh[mf], 0, 0, 0);
            }
        }
        // exp -> qf bf16 hi/lo -> wave-private LDS [n16][m64]
#pragma unroll
        for (int mf = 0; mf < 4; ++mf)
#pragma unroll
            for (int r = 0; r < 4; ++r) {
                float qf = RATIO * (__expf(NORMALIZER * dsh[mf][r]) + KEPS);
                __bf16 hh = (__bf16)qf;
                int nloc = lq * 4 + r;
                qfh[w][nloc][mf * 16 + lm] = hh;
                qfl[w][nloc][mf * 16 + lm] = (__bf16)(qf - (float)hh);
            }
        // out GEMM: acc += qf[n][m] @ ctxT[e][m]
#pragma unroll
        for (int ks = 0; ks < 2; ++ks) {
            bf16x8 af  = *(const bf16x8*)&qfh[w][lm][ks * 32 + lq * 8];
            bf16x8 afl = *(const bf16x8*)&qfl[w][lm][ks * 32 + lq * 8];
#pragma unroll
            for (int ef = 0; ef < 5; ++ef) {
                size_t ca = (size_t)(ef * 16 + lm) * M_ + m0 + ks * 32 + lq * 8;
                bf16x8 bfh = *(const bf16x8*)(cth + ca);
                bf16x8 bfl = *(const bf16x8*)(ctl + ca);
                accO[ef] = __builtin_amdgcn_mfma_f32_16x16x32_bf16(af,  bfh, accO[ef], 0, 0, 0);
                accO[ef] = __builtin_amdgcn_mfma_f32_16x16x32_bf16(afl, bfh, accO[ef], 0, 0, 0);
                accO[ef] = __builtin_amdgcn_mfma_f32_16x16x32_bf16(af,  bfl, accO[ef], 0, 0, 0);
            }
        }
    }

    // denominator: ctx column 64 -> accO[4] col (64 + lm); lm==0 holds den[row]
    float dinv[4];
#pragma unroll
    for (int r = 0; r < 4; ++r) {
        float den = __shfl(accO[4][r], lane & 48);
        dinv[r] = 1.f / den;
    }
#pragma unroll
    for (int ef = 0; ef < 4; ++ef)
#pragma unroll
        for (int r = 0; r < 4; ++r) {
            float o = accO[ef][r] * dinv[r];
            __bf16 hh = (__bf16)o;
            size_t oa = rowbase + (size_t)(nw + lq * 4 + r) * H_ + ef * 16 + lm;
            attnH[oa] = hh;
            attnL[oa] = (__bf16)(o - (float)hh);
        }
}

// ======================================================================
extern "C" void kernel_launch(void* const* d_in, const int* in_sizes, int n_in,
                              void* d_out, int out_size, void* d_ws, size_t ws_size,
                              hipStream_t stream) {
    const float* hs   = (const float*)d_in[0];
    const float* Wq   = (const float*)d_in[1];
    const float* bq   = (const float*)d_in[2];
    const float* Wk   = (const float*)d_in[3];
    const float* bk   = (const float*)d_in[4];
    const float* Wv   = (const float*)d_in[5];
    const float* bv   = (const float*)d_in[6];
    const float* Wo   = (const float*)d_in[7];
    const float* bo   = (const float*)d_in[8];
    const float* proj = (const float*)d_in[9];
    float* out = (float*)d_out;

    const size_t QSZ = (size_t)B_ * N_ * H_;           // 8388608
    const size_t WSZ = (size_t)H_ * H_;                // 1048576
    const size_t CTXT = (size_t)B_ * HEADS_ * EPAD * M_;  // 655360

    __bf16* Qh  = (__bf16*)d_ws;
    __bf16* Ql  = Qh + QSZ;
    __bf16* Kh  = Ql + QSZ;
    __bf16* Kl  = Kh + QSZ;
    __bf16* Vh  = Kl + QSZ;
    __bf16* Vl  = Vh + QSZ;
    __bf16* hsH = Vl + QSZ;      // aliased as attnH after hs consumed
    __bf16* hsL = hsH + QSZ;     // aliased as attnL
    __bf16* WH  = hsL + QSZ;
    __bf16* WL  = WH + 4 * WSZ;
    __bf16* projH = WL + 4 * WSZ;
    __bf16* projL = projH + (size_t)M_ * DH_;
    __bf16* ctxTh = projL + (size_t)M_ * DH_;
    __bf16* ctxTl = ctxTh + CTXT;
    float*  diag  = (float*)(ctxTl + CTXT);
    float*  parts = diag + (size_t)B_ * HEADS_ * N_;
    float*  stab  = parts + 2048;
    float*  ctxp  = stab + 16;

    __bf16 *WqH = WH, *WkH = WH + WSZ, *WvH = WH + 2*WSZ, *WoH = WH + 3*WSZ;
    __bf16 *WqL = WL, *WkL = WL + WSZ, *WvL = WL + 2*WSZ, *WoL = WL + 3*WSZ;

    // 0) splits
    split_bf16<<<QSZ / 4 / 256, 256, 0, stream>>>(hs, hsH, hsL);
    split_w<<<dim3(WSZ / 4 / 256, 4), 256, 0, stream>>>(Wq, Wk, Wv, Wo, WH, WL);
    split_bf16<<<(M_ * DH_) / 4 / 256, 256, 0, stream>>>(proj, projH, projL);

    // 1) Q,K,V = hs @ W^T + b  -> bf16 hi/lo
    gemm_mfma3<true><<<dim3(H_ / 128, (B_ * N_) / 128, 3), 256, 0, stream>>>(
        hsH, hsL, WqH, WqL, WkH, WkL, WvH, WvL, bq, bk, bv,
        nullptr, Qh, Ql, Kh, Kl, Vh, Vl);

    // 2) diag + global stabilizer
    diag_kernel<<<2048, 256, 0, stream>>>(Kh, Kl, diag, parts);
    reduce_stab<<<1, 256, 0, stream>>>(parts, stab, 2048);

    // 3) ctx partials (MFMA)
    ctx_mfma<<<dim3(NSPLIT, 2, B_ * HEADS_), 256, 0, stream>>>(
        Kh, Kl, Vh, Vl, projH, projL, diag, stab, ctxp);

    // 4) reduce partials -> bf16 ctxT
    ctx_reduce<<<(B_ * HEADS_ * EPAD * M_) / 256, 256, 0, stream>>>(ctxp, ctxTh, ctxTl);

    // 5) out (MFMA), writes attn bf16 hi/lo (aliases hs buffers)
    out_mfma<<<dim3(N_ / 64, B_ * HEADS_), 256, 0, stream>>>(
        Qh, Ql, projH, projL, ctxTh, ctxTl, hsH, hsL);

    // 6) final projection fp32 out
    gemm_mfma3<false><<<dim3(H_ / 128, (B_ * N_) / 128, 1), 256, 0, stream>>>(
        hsH, hsL, WoH, WoL, WoH, WoL, WoH, WoL, bo, bo, bo,
        out, nullptr, nullptr, nullptr, nullptr, nullptr, nullptr);
}

// Round 2
// 524.145 us; speedup vs baseline: 1.0449x; 1.0041x over previous
//
#include <hip/hip_runtime.h>
#include <math.h>

#define B_      2
#define N_      4096
#define H_      1024
#define HEADS_  16
#define DH_     64
#define M_      256
#define NSPLIT  8
#define EPAD    80

constexpr float NORMALIZER = 0.35355339059327373f; // 64^-0.25
constexpr float RATIO      = 0.0625f;              // 256^-0.5
constexpr float KEPS       = 1e-3f;

typedef __bf16 bf16x8 __attribute__((ext_vector_type(8)));
typedef __bf16 bf16x4 __attribute__((ext_vector_type(4)));
typedef float  f32x4  __attribute__((ext_vector_type(4)));

// ======================================================================
// Split fp32 -> bf16 (hi, lo)
// ======================================================================
__global__ __launch_bounds__(256) void split_bf16(
    const float* __restrict__ src, __bf16* __restrict__ hi, __bf16* __restrict__ lo)
{
    int i = blockIdx.x * 256 + threadIdx.x;
    float4 v = ((const float4*)src)[i];
    float vv[4] = {v.x, v.y, v.z, v.w};
    bf16x4 h, l;
#pragma unroll
    for (int j = 0; j < 4; ++j) {
        __bf16 hh = (__bf16)vv[j];
        h[j] = hh;
        l[j] = (__bf16)(vv[j] - (float)hh);
    }
    ((bf16x4*)hi)[i] = h;
    ((bf16x4*)lo)[i] = l;
}

__global__ __launch_bounds__(256) void split_w(
    const float* __restrict__ W0, const float* __restrict__ W1,
    const float* __restrict__ W2, const float* __restrict__ W3,
    __bf16* __restrict__ hi, __bf16* __restrict__ lo)
{
    const float* src = W0;
    if (blockIdx.y == 1) src = W1;
    else if (blockIdx.y == 2) src = W2;
    else if (blockIdx.y == 3) src = W3;
    int i = blockIdx.x * 256 + threadIdx.x;
    size_t o = (size_t)blockIdx.y * 262144 + i;
    float4 v = ((const float4*)src)[i];
    float vv[4] = {v.x, v.y, v.z, v.w};
    bf16x4 h, l;
#pragma unroll
    for (int j = 0; j < 4; ++j) {
        __bf16 hh = (__bf16)vv[j];
        h[j] = hh;
        l[j] = (__bf16)(vv[j] - (float)hh);
    }
    ((bf16x4*)hi)[o] = h;
    ((bf16x4*)lo)[o] = l;
}

// ======================================================================
// Split-bf16 MFMA GEMM, C = A@W^T + bias. BF16OUT: write C as bf16 hi/lo.
// 512 threads / 8 waves (wave tile 64x32) for 4 waves/SIMD residency.
// 2-phase pipelined K-loop:
//   - global_load_lds width=16 direct staging (no VGPR roundtrip)
//   - double-buffered linear LDS tiles [128][32] (64 KiB, 2 blk/CU ->
//     16 waves/CU)
//   - counted s_waitcnt vmcnt(4): next tile's 4 loads/wave stay in
//     flight across both barriers (raw s_barrier; no vmcnt(0) in loop)
//   - XOR swizzle (chunk ^= (row>>1)&3) applied to the GLOBAL source at
//     staging and to the ds_read address (linear LDS dest, rule #21) ->
//     fragment reads are 2-way (free) instead of 8-way conflicted
// ======================================================================
template<bool BF16OUT>
__global__ __launch_bounds__(512, 4) void gemm_mfma3(
    const __bf16* __restrict__ Ah, const __bf16* __restrict__ Al,
    const __bf16* __restrict__ Bh0, const __bf16* __restrict__ Bl0,
    const __bf16* __restrict__ Bh1, const __bf16* __restrict__ Bl1,
    const __bf16* __restrict__ Bh2, const __bf16* __restrict__ Bl2,
    const float* __restrict__ bi0, const float* __restrict__ bi1, const float* __restrict__ bi2,
    float* __restrict__ C0,
    __bf16* __restrict__ Ch0, __bf16* __restrict__ Cl0,
    __bf16* __restrict__ Ch1, __bf16* __restrict__ Cl1,
    __bf16* __restrict__ Ch2, __bf16* __restrict__ Cl2)
{
    const __bf16* Bh = Bh0; const __bf16* Bl = Bl0; const float* bias = bi0;
    __bf16* Ch = Ch0; __bf16* Cl = Cl0;
    if (blockIdx.z == 1) { Bh = Bh1; Bl = Bl1; bias = bi1; Ch = Ch1; Cl = Cl1; }
    else if (blockIdx.z == 2) { Bh = Bh2; Bl = Bl2; bias = bi2; Ch = Ch2; Cl = Cl2; }

    // [buf][tile][128*32] linear; tile: 0=Ah 1=Al 2=Bh 3=Bl
    __shared__ alignas(16) __bf16 lds[2][4][128 * 32];

    const int t    = threadIdx.x;
    const int lane = t & 63;
    const int lm   = lane & 15;
    const int lq   = lane >> 4;
    const int w    = t >> 6;
    const int wm   = (w >> 2) * 64;    // m half
    const int wn   = (w & 3) * 32;     // n quarter
    const int m0   = blockIdx.y * 128;
    const int n0   = blockIdx.x * 128;
    const int K    = 1024;
    const int NK   = 32;

    // wave w stages half hw of tile tw; 4 calls x 1KiB per K-step.
    // lane -> (row = c*16 + (lane>>2), slot = lane&3); LDS dest linear.
    // Global column chunk pre-swizzled: chunk = slot ^ ((row>>1)&3) and
    // (row>>1)&3 == (lane>>3)&3 (hw*64 and c*16 don't touch bits 1-2).
    const int tw = w >> 1;
    const int hw = w & 1;
    const __bf16* mysrc = (tw == 0) ? Ah : (tw == 1) ? Al : (tw == 2) ? Bh : Bl;
    const int     rbase = ((tw < 2) ? m0 : n0) + hw * 64;
    const int rsub   = lane >> 2;
    const int slot   = lane & 3;
    const int schunk = slot ^ ((lane >> 3) & 3);
    const __bf16* gbase = mysrc + (size_t)(rbase + rsub) * K + schunk * 8;

    f32x4 acc[4][2];
#pragma unroll
    for (int i = 0; i < 4; ++i)
#pragma unroll
        for (int j = 0; j < 2; ++j) acc[i][j] = (f32x4){0.f, 0.f, 0.f, 0.f};

    // read-side swizzle (same involution). Fragment row r = 16*q + lm, so
    // ((r>>1)&3) == ((lm>>1)&3): swz is lane-constant for the whole kernel.
    const int swz = (lq ^ ((lm >> 1) & 3)) * 8;

    auto stage = [&](int buf, int k0) {
#pragma unroll
        for (int c = 0; c < 4; ++c) {
            const __bf16* g = gbase + (size_t)c * 16 * K + k0;
            __builtin_amdgcn_global_load_lds(
                (const __attribute__((address_space(1))) void*)g,
                (__attribute__((address_space(3))) void*)&lds[buf][tw][(hw * 64 + c * 16) * 32],
                16, 0, 0);
        }
    };

    auto compute = [&](int p) {
        const __bf16* tAh = lds[p][0];
        const __bf16* tAl = lds[p][1];
        const __bf16* tBh = lds[p][2];
        const __bf16* tBl = lds[p][3];
        bf16x8 bh[2], bl[2];
#pragma unroll
        for (int j = 0; j < 2; ++j) {
            int off = (wn + j * 16 + lm) * 32 + swz;
            bh[j] = *(const bf16x8*)&tBh[off];
            bl[j] = *(const bf16x8*)&tBl[off];
        }
#pragma unroll
        for (int i = 0; i < 4; ++i) {
            int off = (wm + i * 16 + lm) * 32 + swz;
            bf16x8 ah = *(const bf16x8*)&tAh[off];
            bf16x8 al = *(const bf16x8*)&tAl[off];
#pragma unroll
            for (int j = 0; j < 2; ++j) {
                acc[i][j] = __builtin_amdgcn_mfma_f32_16x16x32_bf16(ah, bh[j], acc[i][j], 0, 0, 0);
                acc[i][j] = __builtin_amdgcn_mfma_f32_16x16x32_bf16(al, bh[j], acc[i][j], 0, 0, 0);
                acc[i][j] = __builtin_amdgcn_mfma_f32_16x16x32_bf16(ah, bl[j], acc[i][j], 0, 0, 0);
            }
        }
    };

    stage(0, 0);
    int p = 0;
#pragma unroll 1
    for (int kk = 0; kk < NK - 1; ++kk) {
        // issue next K-step's loads (safe: prior reads of buf p^1 finished
        // before the trailing barrier of the previous iteration)
        stage(p ^ 1, (kk + 1) * 32);
        // wait only for MY oldest 4 (current buffer); next 4 stay in flight
        asm volatile("s_waitcnt vmcnt(4)" ::: "memory");
        asm volatile("s_barrier" ::: "memory");   // all waves' current tile landed
        compute(p);
        asm volatile("s_barrier" ::: "memory");   // reads done before overwrite
        p ^= 1;
    }
    asm volatile("s_waitcnt vmcnt(0)" ::: "memory");
    asm volatile("s_barrier" ::: "memory");
    compute(p);

    float bsr[2];
#pragma unroll
    for (int j = 0; j < 2; ++j) bsr[j] = bias[n0 + wn + j * 16 + lm];
#pragma unroll
    for (int i = 0; i < 4; ++i)
#pragma unroll
        for (int r = 0; r < 4; ++r) {
            int rowm = m0 + wm + i * 16 + lq * 4 + r;
#pragma unroll
            for (int j = 0; j < 2; ++j) {
                int col = n0 + wn + j * 16 + lm;
                float o = acc[i][j][r] + bsr[j];
                if (BF16OUT) {
                    __bf16 hh = (__bf16)o;
                    Ch[(size_t)rowm * 1024 + col] = hh;
                    Cl[(size_t)rowm * 1024 + col] = (__bf16)(o - (float)hh);
                } else {
                    C0[(size_t)rowm * 1024 + col] = o;
                }
            }
        }
}

// ======================================================================
// diag_k from bf16 hi/lo K
// ======================================================================
__global__ __launch_bounds__(256) void diag_kernel(
    const __bf16* __restrict__ Kh, const __bf16* __restrict__ Kl,
    float* __restrict__ diag, float* __restrict__ partials)
{
    int gt = blockIdx.x * 256 + threadIdx.x;
    int r  = gt >> 2;
    int q  = gt & 3;
    const bf16x8* ph = (const bf16x8*)(Kh + (size_t)r * 64 + q * 16);
    const bf16x8* pl = (const bf16x8*)(Kl + (size_t)r * 64 + q * 16);
    float s = 0.f;
#pragma unroll
    for (int i = 0; i < 2; ++i) {
        bf16x8 vh = ph[i], vl = pl[i];
#pragma unroll
        for (int j = 0; j < 8; ++j) {
            float x = (float)vh[j] + (float)vl[j];
            s += x * x;
        }
    }
    s += __shfl_xor(s, 1);
    s += __shfl_xor(s, 2);
    float d = -0.5f * s;
    if (q == 0) {
        int h = r & 15, bn = r >> 4;
        int n = bn & 4095, b = bn >> 12;
        diag[(((size_t)b * 16 + h) << 12) + n] = d;
    }
    __shared__ float red[256];
    red[threadIdx.x] = d;
    __syncthreads();
    for (int s2 = 128; s2 > 0; s2 >>= 1) {
        if (threadIdx.x < s2) red[threadIdx.x] = fmaxf(red[threadIdx.x], red[threadIdx.x + s2]);
        __syncthreads();
    }
    if (threadIdx.x == 0) partials[blockIdx.x] = red[0];
}

__global__ __launch_bounds__(256) void reduce_stab(
    const float* __restrict__ partials, float* __restrict__ stab, int n)
{
    float m = -3.0e38f;
    for (int i = threadIdx.x; i < n; i += 256) m = fmaxf(m, partials[i]);
    __shared__ float red[256];
    red[threadIdx.x] = m;
    __syncthreads();
    for (int s2 = 128; s2 > 0; s2 >>= 1) {
        if (threadIdx.x < s2) red[threadIdx.x] = fmaxf(red[threadIdx.x], red[threadIdx.x + s2]);
        __syncthreads();
    }
    if (threadIdx.x == 0) stab[0] = red[0];
}

// ======================================================================
// ctx via MFMA. grid (NSPLIT, 2 m-halves, 32 bh). 4 waves, wave owns 32 m.
// dash: D[n64, m32/wave] = K@proj^T (3 split products, operands from global)
// exp -> kf bf16 hi/lo -> LDS transpose kfT[m][n] -> ctx += kfT @ vT[e][n]
// e=64 is ones (k_cumsum); e 65..79 zero pad. fp32 partials out [s][bh][e][m].
// ======================================================================
__global__ __launch_bounds__(256) void ctx_mfma(
    const __bf16* __restrict__ Kh, const __bf16* __restrict__ Kl,
    const __bf16* __restrict__ Vh, const __bf16* __restrict__ Vl,
    const __bf16* __restrict__ projH, const __bf16* __restrict__ projL,
    const float* __restrict__ diag, const float* __restrict__ stabp,
    float* __restrict__ ctxp)
{
    __shared__ alignas(16) char ldsbuf[59904];
    __shared__ float dg[64];
    __bf16* kfTh = (__bf16*)ldsbuf;              // [128][72]
    __bf16* kfTl = kfTh + 9216;                  // [128][72]
    __bf16* vTh  = kfTl + 9216;                  // [80][72]
    __bf16* vTl  = vTh + 5760;                   // [80][72]
    float*  ctxe = (float*)ldsbuf;               // [128][81] (epilogue alias)

    const int t    = threadIdx.x;
    const int lane = t & 63;
    const int w    = t >> 6;
    const int lm   = lane & 15;
    const int lq   = lane >> 4;
    const int bh   = blockIdx.z;
    const int b    = bh >> 4, h = bh & 15;
    const int mh   = blockIdx.y;
    const int slice = blockIdx.x;
    const int mwave = mh * 128 + w * 32;          // global m base for wave
    const float stab = stabp[0];
    const size_t rowbase = (size_t)b * N_ * H_ + (size_t)h * DH_;
    const float* diag_bh = diag + (size_t)bh * N_;

    // vT constant rows: e=64 -> ones (hi), e>64 -> zero
    for (int idx = t; idx < 16 * 72; idx += 256) {
        int e = 64 + idx / 72, n = idx % 72;
        vTh[e * 72 + n] = (e == 64 && n < 64) ? (__bf16)1.0f : (__bf16)0.0f;
        vTl[e * 72 + n] = (__bf16)0.0f;
    }

    // proj B-frags, register-cached for whole kernel: [mf][ks]
    bf16x8 ph[2][2], pl[2][2];
#pragma unroll
    for (int mf = 0; mf < 2; ++mf)
#pragma unroll
        for (int ks = 0; ks < 2; ++ks) {
            size_t pa = (size_t)(mwave + mf * 16 + lm) * 64 + ks * 32 + lq * 8;
            ph[mf][ks] = *(const bf16x8*)(projH + pa);
            pl[mf][ks] = *(const bf16x8*)(projL + pa);
        }

    f32x4 acc[2][5];
#pragma unroll
    for (int mf = 0; mf < 2; ++mf)
#pragma unroll
        for (int ef = 0; ef < 5; ++ef) acc[mf][ef] = (f32x4){0.f, 0.f, 0.f, 0.f};

    for (int tile = 0; tile < 8; ++tile) {
        const int n0 = slice * (N_ / NSPLIT) + tile * 64;
        __syncthreads();   // barrier A: prior GEMM reads of vT done

        // stage vT rows 0..63 (transpose V[n][d] -> vT[d][n])
        {
            int nl = t >> 2, dc = (t & 3) * 16;
            size_t va = rowbase + (size_t)(n0 + nl) * H_ + dc;
            bf16x8 v0 = *(const bf16x8*)(Vh + va);
            bf16x8 v1 = *(const bf16x8*)(Vh + va + 8);
            bf16x8 u0 = *(const bf16x8*)(Vl + va);
            bf16x8 u1 = *(const bf16x8*)(Vl + va + 8);
#pragma unroll
            for (int j = 0; j < 8; ++j) {
                vTh[(dc + j) * 72 + nl]     = v0[j];
                vTh[(dc + 8 + j) * 72 + nl] = v1[j];
                vTl[(dc + j) * 72 + nl]     = u0[j];
                vTl[(dc + 8 + j) * 72 + nl] = u1[j];
            }
        }
        if (t < 64) dg[t] = diag_bh[n0 + t] - stab;

        // dash MFMA (global operands, no LDS dependency)
        f32x4 dsh[4][2];
#pragma unroll
        for (int nf = 0; nf < 4; ++nf) {
#pragma unroll
            for (int mf = 0; mf < 2; ++mf) dsh[nf][mf] = (f32x4){0.f, 0.f, 0.f, 0.f};
            bf16x8 ah[2], al[2];
#pragma unroll
            for (int ks = 0; ks < 2; ++ks) {
                size_t ka = rowbase + (size_t)(n0 + nf * 16 + lm) * H_ + ks * 32 + lq * 8;
                ah[ks] = *(const bf16x8*)(Kh + ka);
                al[ks] = *(const bf16x8*)(Kl + ka);
            }
#pragma unroll
            for (int mf = 0; mf < 2; ++mf)
#pragma unroll
                for (int ks = 0; ks < 2; ++ks) {
                    dsh[nf][mf] = __builtin_amdgcn_mfma_f32_16x16x32_bf16(ah[ks], ph[mf][ks], dsh[nf][mf], 0, 0, 0);
                    dsh[nf][mf] = __builtin_amdgcn_mfma_f32_16x16x32_bf16(al[ks], ph[mf][ks], dsh[nf][mf], 0, 0, 0);
                    dsh[nf][mf] = __builtin_amdgcn_mfma_f32_16x16x32_bf16(ah[ks], pl[mf][ks], dsh[nf][mf], 0, 0, 0);
                }
        }

        __syncthreads();   // barrier B: vT + dg staged

        // exp -> kf bf16 hi/lo -> kfT (wave-private rows)
#pragma unroll
        for (int nf = 0; nf < 4; ++nf) {
            float4 dgv = *(const float4*)&dg[nf * 16 + lq * 4];
            float dga[4] = {dgv.x, dgv.y, dgv.z, dgv.w};
#pragma unroll
            for (int mf = 0; mf < 2; ++mf) {
                int mrow = w * 32 + mf * 16 + lm;   // block-local m row
#pragma unroll
                for (int r = 0; r < 4; ++r) {
                    float kf = RATIO * (__expf(dga[r] + NORMALIZER * dsh[nf][mf][r]) + KEPS);
                    __bf16 hh = (__bf16)kf;
                    int nloc = nf * 16 + lq * 4 + r;
                    kfTh[mrow * 72 + nloc] = hh;
                    kfTl[mrow * 72 + nloc] = (__bf16)(kf - (float)hh);
                }
            }
        }

        // ctx accumulate: acc[mf][ef] += kfT[m][n] @ vT[e][n]
#pragma unroll
        for (int ks = 0; ks < 2; ++ks) {
#pragma unroll
            for (int mf = 0; mf < 2; ++mf) {
                bf16x8 af = *(const bf16x8*)&kfTh[(w * 32 + mf * 16 + lm) * 72 + ks * 32 + lq * 8];
                bf16x8 afl = *(const bf16x8*)&kfTl[(w * 32 + mf * 16 + lm) * 72 + ks * 32 + lq * 8];
#pragma unroll
                for (int ef = 0; ef < 5; ++ef) {
                    bf16x8 bfh = *(const bf16x8*)&vTh[(ef * 16 + lm) * 72 + ks * 32 + lq * 8];
                    bf16x8 bfl = *(const bf16x8*)&vTl[(ef * 16 + lm) * 72 + ks * 32 + lq * 8];
                    acc[mf][ef] = __builtin_amdgcn_mfma_f32_16x16x32_bf16(af,  bfh, acc[mf][ef], 0, 0, 0);
                    acc[mf][ef] = __builtin_amdgcn_mfma_f32_16x16x32_bf16(afl, bfh, acc[mf][ef], 0, 0, 0);
                    acc[mf][ef] = __builtin_amdgcn_mfma_f32_16x16x32_bf16(af,  bfl, acc[mf][ef], 0, 0, 0);
                }
            }
        }
    }

    // epilogue: acc -> ctxe[m][e] (fp32, pad 81) -> coalesced global [s][bh][e][m]
    __syncthreads();
#pragma unroll
    for (int mf = 0; mf < 2; ++mf)
#pragma unroll
        for (int ef = 0; ef < 5; ++ef)
#pragma unroll
            for (int r = 0; r < 4; ++r) {
                int ml = w * 32 + mf * 16 + lq * 4 + r;
                int e  = ef * 16 + lm;
                ctxe[ml * 81 + e] = acc[mf][ef][r];
            }
    __syncthreads();
    const size_t SLICE = (size_t)(B_ * HEADS_) * EPAD * M_;
    const size_t obase = (size_t)slice * SLICE + (size_t)bh * EPAD * M_;
    for (int i = t; i < EPAD * 128; i += 256) {
        int e = i >> 7, ml = i & 127;
        ctxp[obase + (size_t)e * M_ + mh * 128 + ml] = ctxe[ml * 81 + e];
    }
}

// ======================================================================
// Reduce ctx partials over slices -> bf16 hi/lo ctxT[bh][e][m]
// ======================================================================
__global__ __launch_bounds__(256) void ctx_reduce(
    const float* __restrict__ ctxp, __bf16* __restrict__ ctxTh, __bf16* __restrict__ ctxTl)
{
    int idx = blockIdx.x * 256 + threadIdx.x;     // [0, 32*80*256)
    const size_t SLICE = (size_t)(B_ * HEADS_) * EPAD * M_;
    float s = 0.f;
#pragma unroll
    for (int k = 0; k < NSPLIT; ++k) s += ctxp[(size_t)k * SLICE + idx];
    __bf16 hh = (__bf16)s;
    ctxTh[idx] = hh;
    ctxTl[idx] = (__bf16)(s - (float)hh);
}

// ======================================================================
// out via MFMA. grid (N/64, 32 bh). 4 waves, wave owns 16 n rows. No barriers.
// dash D[n16, m64-chunk] -> qf -> wave-private LDS transpose -> acc += qf@ctxT.
// Column 64 of ctxT = k_cumsum -> denominator; shfl-broadcast; bf16 hi/lo out.
// ======================================================================
__global__ __launch_bounds__(256) void out_mfma(
    const __bf16* __restrict__ Qh, const __bf16* __restrict__ Ql,
    const __bf16* __restrict__ projH, const __bf16* __restrict__ projL,
    const __bf16* __restrict__ ctxTh, const __bf16* __restrict__ ctxTl,
    __bf16* __restrict__ attnH, __bf16* __restrict__ attnL)
{
    __shared__ alignas(16) __bf16 qfh[4][16][72];
    __shared__ alignas(16) __bf16 qfl[4][16][72];

    const int t    = threadIdx.x;
    const int lane = t & 63;
    const int w    = t >> 6;
    const int lm   = lane & 15;
    const int lq   = lane >> 4;
    const int bh   = blockIdx.y;
    const int b    = bh >> 4, h = bh & 15;
    const int nw   = blockIdx.x * 64 + w * 16;    // wave's n base
    const size_t rowbase = (size_t)b * N_ * H_ + (size_t)h * DH_;

    // A dash frags (q rows), loaded once
    bf16x8 qh_[2], ql_[2];
#pragma unroll
    for (int ks = 0; ks < 2; ++ks) {
        size_t qa = rowbase + (size_t)(nw + lm) * H_ + ks * 32 + lq * 8;
        qh_[ks] = *(const bf16x8*)(Qh + qa);
        ql_[ks] = *(const bf16x8*)(Ql + qa);
    }

    const __bf16* cth = ctxTh + (size_t)bh * EPAD * M_;
    const __bf16* ctl = ctxTl + (size_t)bh * EPAD * M_;

    f32x4 accO[5];
#pragma unroll
    for (int ef = 0; ef < 5; ++ef) accO[ef] = (f32x4){0.f, 0.f, 0.f, 0.f};

    for (int mc = 0; mc < 4; ++mc) {
        const int m0 = mc * 64;
        // dash
        f32x4 dsh[4];
#pragma unroll
        for (int mf = 0; mf < 4; ++mf) {
            dsh[mf] = (f32x4){0.f, 0.f, 0.f, 0.f};
#pragma unroll
            for (int ks = 0; ks < 2; ++ks) {
                size_t pa = (size_t)(m0 + mf * 16 + lm) * 64 + ks * 32 + lq * 8;
                bf16x8 ph = *(const bf16x8*)(projH + pa);
                bf16x8 pl = *(const bf16x8*)(projL + pa);
                dsh[mf] = __builtin_amdgcn_mfma_f32_16x16x32_bf16(qh_[ks], ph, dsh[mf], 0, 0, 0);
                dsh[mf] = __builtin_amdgcn_mfma_f32_16x16x32_bf16(ql_[ks], ph, dsh[mf], 0, 0, 0);
                dsh[mf] = __builtin_amdgcn_mfma_f32_16x16x32_bf16(qh_[ks], pl, dsh[mf], 0, 0, 0);
            }
        }
        // exp -> qf bf16 hi/lo -> wave-private LDS [n16][m64]
#pragma unroll
        for (int mf = 0; mf < 4; ++mf)
#pragma unroll
            for (int r = 0; r < 4; ++r) {
                float qf = RATIO * (__expf(NORMALIZER * dsh[mf][r]) + KEPS);
                __bf16 hh = (__bf16)qf;
                int nloc = lq * 4 + r;
                qfh[w][nloc][mf * 16 + lm] = hh;
                qfl[w][nloc][mf * 16 + lm] = (__bf16)(qf - (float)hh);
            }
        // out GEMM: acc += qf[n][m] @ ctxT[e][m]
#pragma unroll
        for (int ks = 0; ks < 2; ++ks) {
            bf16x8 af  = *(const bf16x8*)&qfh[w][lm][ks * 32 + lq * 8];
            bf16x8 afl = *(const bf16x8*)&qfl[w][lm][ks * 32 + lq * 8];
#pragma unroll
            for (int ef = 0; ef < 5; ++ef) {
                size_t ca = (size_t)(ef * 16 + lm) * M_ + m0 + ks * 32 + lq * 8;
                bf16x8 bfh = *(const bf16x8*)(cth + ca);
                bf16x8 bfl = *(const bf16x8*)(ctl + ca);
                accO[ef] = __builtin_amdgcn_mfma_f32_16x16x32_bf16(af,  bfh, accO[ef], 0, 0, 0);
                accO[ef] = __builtin_amdgcn_mfma_f32_16x16x32_bf16(afl, bfh, accO[ef], 0, 0, 0);
                accO[ef] = __builtin_amdgcn_mfma_f32_16x16x32_bf16(af,  bfl, accO[ef], 0, 0, 0);
            }
        }
    }

    // denominator: ctx column 64 -> accO[4] col (64 + lm); lm==0 holds den[row]
    float dinv[4];
#pragma unroll
    for (int r = 0; r < 4; ++r) {
        float den = __shfl(accO[4][r], lane & 48);
        dinv[r] = 1.f / den;
    }
#pragma unroll
    for (int ef = 0; ef < 4; ++ef)
#pragma unroll
        for (int r = 0; r < 4; ++r) {
            float o = accO[ef][r] * dinv[r];
            __bf16 hh = (__bf16)o;
            size_t oa = rowbase + (size_t)(nw + lq * 4 + r) * H_ + ef * 16 + lm;
            attnH[oa] = hh;
            attnL[oa] = (__bf16)(o - (float)hh);
        }
}

// ======================================================================
extern "C" void kernel_launch(void* const* d_in, const int* in_sizes, int n_in,
                              void* d_out, int out_size, void* d_ws, size_t ws_size,
                              hipStream_t stream) {
    const float* hs   = (const float*)d_in[0];
    const float* Wq   = (const float*)d_in[1];
    const float* bq   = (const float*)d_in[2];
    const float* Wk   = (const float*)d_in[3];
    const float* bk   = (const float*)d_in[4];
    const float* Wv   = (const float*)d_in[5];
    const float* bv   = (const float*)d_in[6];
    const float* Wo   = (const float*)d_in[7];
    const float* bo   = (const float*)d_in[8];
    const float* proj = (const float*)d_in[9];
    float* out = (float*)d_out;

    const size_t QSZ = (size_t)B_ * N_ * H_;           // 8388608
    const size_t WSZ = (size_t)H_ * H_;                // 1048576
    const size_t CTXT = (size_t)B_ * HEADS_ * EPAD * M_;  // 655360

    __bf16* Qh  = (__bf16*)d_ws;
    __bf16* Ql  = Qh + QSZ;
    __bf16* Kh  = Ql + QSZ;
    __bf16* Kl  = Kh + QSZ;
    __bf16* Vh  = Kl + QSZ;
    __bf16* Vl  = Vh + QSZ;
    __bf16* hsH = Vl + QSZ;      // aliased as attnH after hs consumed
    __bf16* hsL = hsH + QSZ;     // aliased as attnL
    __bf16* WH  = hsL + QSZ;
    __bf16* WL  = WH + 4 * WSZ;
    __bf16* projH = WL + 4 * WSZ;
    __bf16* projL = projH + (size_t)M_ * DH_;
    __bf16* ctxTh = projL + (size_t)M_ * DH_;
    __bf16* ctxTl = ctxTh + CTXT;
    float*  diag  = (float*)(ctxTl + CTXT);
    float*  parts = diag + (size_t)B_ * HEADS_ * N_;
    float*  stab  = parts + 2048;
    float*  ctxp  = stab + 16;

    __bf16 *WqH = WH, *WkH = WH + WSZ, *WvH = WH + 2*WSZ, *WoH = WH + 3*WSZ;
    __bf16 *WqL = WL, *WkL = WL + WSZ, *WvL = WL + 2*WSZ, *WoL = WL + 3*WSZ;

    // 0) splits
    split_bf16<<<QSZ / 4 / 256, 256, 0, stream>>>(hs, hsH, hsL);
    split_w<<<dim3(WSZ / 4 / 256, 4), 256, 0, stream>>>(Wq, Wk, Wv, Wo, WH, WL);
    split_bf16<<<(M_ * DH_) / 4 / 256, 256, 0, stream>>>(proj, projH, projL);

    // 1) Q,K,V = hs @ W^T + b  -> bf16 hi/lo
    gemm_mfma3<true><<<dim3(H_ / 128, (B_ * N_) / 128, 3), 512, 0, stream>>>(
        hsH, hsL, WqH, WqL, WkH, WkL, WvH, WvL, bq, bk, bv,
        nullptr, Qh, Ql, Kh, Kl, Vh, Vl);

    // 2) diag + global stabilizer
    diag_kernel<<<2048, 256, 0, stream>>>(Kh, Kl, diag, parts);
    reduce_stab<<<1, 256, 0, stream>>>(parts, stab, 2048);

    // 3) ctx partials (MFMA)
    ctx_mfma<<<dim3(NSPLIT, 2, B_ * HEADS_), 256, 0, stream>>>(
        Kh, Kl, Vh, Vl, projH, projL, diag, stab, ctxp);

    // 4) reduce partials -> bf16 ctxT
    ctx_reduce<<<(B_ * HEADS_ * EPAD * M_) / 256, 256, 0, stream>>>(ctxp, ctxTh, ctxTl);

    // 5) out (MFMA), writes attn bf16 hi/lo (aliases hs buffers)
    out_mfma<<<dim3(N_ / 64, B_ * HEADS_), 256, 0, stream>>>(
        Qh, Ql, projH, projL, ctxTh, ctxTl, hsH, hsL);

    // 6) final projection fp32 out
    gemm_mfma3<false><<<dim3(H_ / 128, (B_ * N_) / 128, 1), 512, 0, stream>>>(
        hsH, hsL, WoH, WoL, WoH, WoL, WoH, WoL, bo, bo, bo,
        out, nullptr, nullptr, nullptr, nullptr, nullptr, nullptr);
}